// Round 1
// baseline (176.309 us; speedup 1.0000x reference)
//
#include <hip/hip_runtime.h>
#include <math.h>

// Problem constants (B, C, H, W) = (32, 10, 192, 320), fp32.
constexpr int B_ = 32, C_ = 10, H_ = 192, W_ = 320;
constexpr int HW_  = H_ * W_;        // 61440 (divisible by 4)
constexpr int CHW_ = C_ * HW_;       // 614400
constexpr int NPTS = B_ * HW_;       // 1966080 spatial points
constexpr int NV4  = NPTS / 4;       // 491520 float4 points
constexpr int NBLK = NV4 / 256;      // 1920 blocks, exact cover

// Accumulator slots in workspace (padded to 128 B apart to decontend atomics)
// 0: nv            (sum mvf)
// 1: num_pos
// 2: sum pos*(g0-r0)^2*log(safe+EPS)           (pos_term = -this)
// 3: sum neg*r0^2*log(1+EPS-safe)*(1-g0)^4     (neg_term = -this)
// 4: s_pos   sl1(r1-g1)+sl1(r2-g2)             masked
// 5: s_len1  sl1(r3-g3)+sl1(r6-g6)             masked
// 6: s_len2  sl1(r3-g6)+sl1(r6-g3)             masked
// 7: s_trig1 (r4-g4)^2+(r7-g7)^2+(r5-g5)^2+(r8-g8)^2  masked
// 8: s_trig2 (r4-g7)^2+(r7-g4)^2+(r5-g8)^2+(r8-g5)^2  masked
// 9: s_const (1-r5^2-r4^2)^2+(1-r8^2-r7^2)^2   masked
// 10: s_h    sl1(r9-g9)                        masked
#define NACC 11
#define PAD  32   // floats (128 B) between slots

__device__ __forceinline__ float sl1f(float d) {
    float ad = fabsf(d);
    return ad < 1.0f ? 0.5f * d * d : ad - 0.5f;
}

__global__ __launch_bounds__(256) void loss_main(
    const float* __restrict__ re, const float* __restrict__ gt,
    float* __restrict__ ws)
{
    const int tid = blockIdx.x * 256 + threadIdx.x;
    float acc[NACC];
#pragma unroll
    for (int i = 0; i < NACC; ++i) acc[i] = 0.0f;

    if (tid < NV4) {
        const int p = tid * 4;
        const int b = p / HW_;
        const int s = p - b * HW_;
        const float* rp = re + (size_t)b * CHW_ + s;
        const float* gp = gt + (size_t)b * CHW_ + s;

        const float4 g4 = *(const float4*)gp;
        const float4 r4 = *(const float4*)rp;
        float gv[4] = {g4.x, g4.y, g4.z, g4.w};
        float rv[4] = {r4.x, r4.y, r4.z, r4.w};
        float mv[4];
        float any = 0.0f;

#pragma unroll
        for (int j = 0; j < 4; ++j) {
            const float g = gv[j], r = rv[j];
            const float m = (g == 1.0f) ? 1.0f : 0.0f;
            mv[j] = m; any += m;
            acc[0] += m;
            const float pos = (g >= 0.1f) ? 1.0f : 0.0f;
            const float neg = ((g >= 0.0f) && (g < 0.1f)) ? 1.0f : 0.0f;
            acc[1] += pos;
            const float safe = fminf(fmaxf(r, 1e-6f), 1.0f - 1e-6f);
            const float d = g - r;
            acc[2] += pos * (d * d) * logf(safe + 6e-8f);
            const float omg = 1.0f - g;
            const float omg2 = omg * omg;
            acc[3] += neg * (r * r) * logf(1.0f + 6e-8f - safe) * (omg2 * omg2);
        }

        // channels 1..9 only matter where gt0 == 1.0 (~5% of points);
        // exec-masked loads skip untouched sectors for ~80% of threads.
        if (any != 0.0f) {
            float rc[9][4], gc[9][4];
#pragma unroll
            for (int c = 0; c < 9; ++c) {
                const float4 t = *(const float4*)(rp + (c + 1) * HW_);
                rc[c][0] = t.x; rc[c][1] = t.y; rc[c][2] = t.z; rc[c][3] = t.w;
                const float4 u = *(const float4*)(gp + (c + 1) * HW_);
                gc[c][0] = u.x; gc[c][1] = u.y; gc[c][2] = u.z; gc[c][3] = u.w;
            }
#pragma unroll
            for (int j = 0; j < 4; ++j) {
                const float m = mv[j];
                const float r1 = rc[0][j], r2 = rc[1][j], r3 = rc[2][j];
                const float r4v = rc[3][j], r5 = rc[4][j], r6 = rc[5][j];
                const float r7 = rc[6][j], r8 = rc[7][j], r9 = rc[8][j];
                const float g1 = gc[0][j], g2 = gc[1][j], g3 = gc[2][j];
                const float g4v = gc[3][j], g5 = gc[4][j], g6 = gc[5][j];
                const float g7 = gc[6][j], g8 = gc[7][j], g9 = gc[8][j];

                acc[4] += m * (sl1f(r1 - g1) + sl1f(r2 - g2));
                acc[5] += m * (sl1f(r3 - g3) + sl1f(r6 - g6));
                acc[6] += m * (sl1f(r3 - g6) + sl1f(r6 - g3));
                const float d44 = r4v - g4v, d77 = r7 - g7;
                const float d55 = r5 - g5,  d88 = r8 - g8;
                acc[7] += m * (d44 * d44 + d77 * d77 + d55 * d55 + d88 * d88);
                const float d47 = r4v - g7, d74 = r7 - g4v;
                const float d58 = r5 - g8,  d85 = r8 - g5;
                acc[8] += m * (d47 * d47 + d74 * d74 + d58 * d58 + d85 * d85);
                const float c1 = 1.0f - r5 * r5 - r4v * r4v;
                const float c2 = 1.0f - r8 * r8 - r7 * r7;
                acc[9] += m * (c1 * c1 + c2 * c2);
                acc[10] += m * sl1f(r9 - g9);
            }
        }
    }

    // block reduction: wave shuffle (64 lanes) -> LDS (4 waves) -> atomic
    __shared__ float smem[NACC][4];
    const int lane = threadIdx.x & 63;
    const int wid  = threadIdx.x >> 6;
#pragma unroll
    for (int i = 0; i < NACC; ++i) {
        float v = acc[i];
#pragma unroll
        for (int off = 32; off > 0; off >>= 1) v += __shfl_down(v, off, 64);
        if (lane == 0) smem[i][wid] = v;
    }
    __syncthreads();
    if (threadIdx.x < NACC) {
        const int i = threadIdx.x;
        const float v = smem[i][0] + smem[i][1] + smem[i][2] + smem[i][3];
        atomicAdd(&ws[i * PAD], v);
    }
}

__global__ void loss_finalize(const float* __restrict__ ws, float* __restrict__ out)
{
    const float nv     = ws[0 * PAD];
    const float npos   = ws[1 * PAD];
    const float pterm  = -ws[2 * PAD];
    const float nterm  = -ws[3 * PAD];
    const float focal  = (npos == 0.0f) ? nterm : (pterm + nterm) / npos;

    const float inv2nv = 1.0f / (2.0f * nv);
    const float invnv  = 1.0f / nv;

    const float pos_loss = 1.0f * ws[4 * PAD] * inv2nv;           // POS_W
    const float lv1      = 0.1f * ws[5 * PAD] * inv2nv;           // LEN_W
    const float lv2      = 0.1f * ws[6 * PAD] * inv2nv;
    const float tv1      = 1.0f * ws[7 * PAD] * inv2nv;           // TRIG_W
    const float tv2      = 1.0f * ws[8 * PAD] * inv2nv;
    const float cl       = 0.5f * ws[9 * PAD] * invnv;            // CONST_W
    const float hl       = 0.1f * ws[10 * PAD] * invnv;           // LEN_W

    const float dims = fminf(lv1 + tv1, lv2 + tv2) + hl;
    out[0] = 1.0f * focal + pos_loss + dims + cl;                 // CONF_W
}

extern "C" void kernel_launch(void* const* d_in, const int* in_sizes, int n_in,
                              void* d_out, int out_size, void* d_ws, size_t ws_size,
                              hipStream_t stream)
{
    const float* re = (const float*)d_in[0];
    const float* gt = (const float*)d_in[1];
    float* ws  = (float*)d_ws;
    float* out = (float*)d_out;

    // ws is poisoned 0xAA before every timed launch — zero the accumulators.
    hipMemsetAsync(d_ws, 0, NACC * PAD * sizeof(float), stream);
    loss_main<<<NBLK, 256, 0, stream>>>(re, gt, ws);
    loss_finalize<<<1, 1, 0, stream>>>(ws, out);
}